// Round 3
// baseline (2179.853 us; speedup 1.0000x reference)
//
#include <hip/hip_runtime.h>

#define NKER  128
#define INDIM 1024
#define UNITS 1024

typedef __attribute__((ext_vector_type(8)))  short          bf16x8;
typedef __attribute__((ext_vector_type(4)))  float          f32x4;
typedef __attribute__((ext_vector_type(4)))  unsigned short u16x4;
typedef __attribute__((ext_vector_type(8)))  unsigned short u16x8;

__device__ __forceinline__ unsigned short f2bf(float f) {
    // RNE fp32 -> bf16 (compiler emits v_cvt_pk_bf16_f32 for adjacent pairs)
    return __builtin_bit_cast(unsigned short, static_cast<__bf16>(f));
}

// swizzled LDS element index for (row r, k in 0..31), 16B-unit XOR swizzle
// verified conflict-free (rounds 1-2: SQ_LDS_BANK_CONFLICT == 0)
__device__ __forceinline__ int swzidx(int r, int k) {
    return r * 32 + ((((k >> 3) ^ ((r >> 1) & 3)) << 3) | (k & 7));
}

// __launch_bounds__(512, 6): 6 waves/EU -> 3 workgroups/CU resident.
// LDS 48KB x 3 = 144KB <= 160KB is the binding constraint; VGPR=64 is fine.
__global__ void __launch_bounds__(512, 6)
dense_local(const float* __restrict__ X, const float* __restrict__ Kn,
            float* __restrict__ Out)
{
    __shared__ __align__(16) unsigned short lA[2][256 * 32];  // 32 KB total
    __shared__ __align__(16) unsigned short lB[2][128 * 32];  // 16 KB total

    // XCD swizzle: 2048 wgs, 256/XCD, k-major inside an XCD chunk (bijective)
    const int bid  = blockIdx.x;
    const int wg   = (bid & 7) * 256 + (bid >> 3);
    const int kidx = wg >> 4;          // 0..127
    const int tile = wg & 15;
    const int mt   = tile >> 3;        // 0..1  (M tiles of 256 over 512)
    const int nt   = tile & 7;         // 0..7  (N tiles of 128 over 1024)

    const int t   = threadIdx.x;
    const int l   = t & 63;
    const int w   = t >> 6;            // 0..7
    const int wm  = w >> 1;            // 0..3  wave m-quadrant (64 rows each)
    const int wn  = w & 1;             // 0..1  wave n-half (64 cols each)
    const int l15 = l & 15, g = l >> 4;

    const size_t MROW = (size_t)NKER * INDIM; // 131072: row stride of x / out

    const float* Abase = X   + (size_t)mt * 256 * MROW + (size_t)kidx * INDIM;
    const float* Bbase = Kn  + (size_t)kidx * INDIM * UNITS + nt * 128;
    float*       Cbase = Out + (size_t)mt * 256 * MROW + (size_t)kidx * UNITS + nt * 128;

    // staging maps
    const int ar0 = t >> 3;            // A: rows 0..63 (+p*64)
    const int ak4 = (t & 7) << 2;      // A: k quad 0,4,...,28
    const int bn  = t & 127;           // B: column 0..127 (lane-consecutive)
    const int bkh = t >> 7;            // B: k-octet 0..3

    f32x4 acc[4][4];
#pragma unroll
    for (int mi = 0; mi < 4; ++mi)
#pragma unroll
        for (int ni = 0; ni < 4; ++ni)
            acc[mi][ni] = f32x4{0.f, 0.f, 0.f, 0.f};

    f32x4 av[4];
    float bv[8];

    auto loadg = [&](int kc) {
#pragma unroll
        for (int p = 0; p < 4; ++p)
            av[p] = *(const f32x4*)(Abase + (size_t)(ar0 + p * 64) * MROW + kc + ak4);
        const float* bp = Bbase + (size_t)(kc + bkh * 8) * UNITS + bn;
#pragma unroll
        for (int j = 0; j < 8; ++j)
            bv[j] = bp[(size_t)j * UNITS];   // 64 consecutive lanes = 256B coalesced
    };

    auto writes = [&](int bb) {
#pragma unroll
        for (int p = 0; p < 4; ++p) {
            u16x4 h;
#pragma unroll
            for (int c = 0; c < 4; ++c) h[c] = f2bf(av[p][c]);
            *(u16x4*)&lA[bb][swzidx(ar0 + p * 64, ak4)] = h;
        }
        u16x8 h0;
#pragma unroll
        for (int j = 0; j < 8; ++j) h0[j] = f2bf(bv[j]);
        // transpose happens here: row = n, k-contiguous, one packed b128 write
        *(u16x8*)&lB[bb][swzidx(bn, bkh * 8)] = h0;
    };

    auto compute = [&](int bb) {
        bf16x8 af[4], bfr[4];
#pragma unroll
        for (int mi = 0; mi < 4; ++mi) {
            const int r = wm * 64 + mi * 16 + l15;
            af[mi] = *(const bf16x8*)&lA[bb][swzidx(r, g * 8)];
        }
#pragma unroll
        for (int ni = 0; ni < 4; ++ni) {
            const int r = wn * 64 + ni * 16 + l15;
            bfr[ni] = *(const bf16x8*)&lB[bb][swzidx(r, g * 8)];
        }
#pragma unroll
        for (int mi = 0; mi < 4; ++mi)
#pragma unroll
            for (int ni = 0; ni < 4; ++ni)
                acc[mi][ni] = __builtin_amdgcn_mfma_f32_16x16x32_bf16(
                    af[mi], bfr[ni], acc[mi][ni], 0, 0, 0);
    };

    loadg(0);
    writes(0);
    __syncthreads();

    int bb = 0;
#pragma unroll 1
    for (int step = 0; step < 32; ++step) {
        if (step < 31) loadg((step + 1) * 32);  // issue next-tile loads early
        compute(bb);
        __syncthreads();
        if (step < 31) writes(bb ^ 1);
        __syncthreads();
        bb ^= 1;
    }

    // epilogue: softplus + store (C/D layout: col=lane&15, row=(lane>>4)*4+reg)
#pragma unroll
    for (int mi = 0; mi < 4; ++mi) {
#pragma unroll
        for (int ni = 0; ni < 4; ++ni) {
            const int n = wn * 64 + ni * 16 + l15;
#pragma unroll
            for (int r = 0; r < 4; ++r) {
                const int m = wm * 64 + mi * 16 + g * 4 + r;
                const float v  = acc[mi][ni][r];
                const float sp = fmaxf(v, 0.0f) + log1pf(__expf(-fabsf(v)));
                Cbase[(size_t)m * MROW + n] = sp;
            }
        }
    }
}

extern "C" void kernel_launch(void* const* d_in, const int* in_sizes, int n_in,
                              void* d_out, int out_size, void* d_ws, size_t ws_size,
                              hipStream_t stream) {
    const float* X  = (const float*)d_in[0];
    const float* Kn = (const float*)d_in[1];
    float* O = (float*)d_out;
    dense_local<<<2048, 512, 0, stream>>>(X, Kn, O);
}

// Round 4
// 484.968 us; speedup vs baseline: 4.4948x; 4.4948x over previous
//
#include <hip/hip_runtime.h>

#define NKER  128
#define INDIM 1024
#define UNITS 1024

typedef __attribute__((ext_vector_type(8)))  short          bf16x8;
typedef __attribute__((ext_vector_type(4)))  float          f32x4;
typedef __attribute__((ext_vector_type(4)))  unsigned short u16x4;
typedef __attribute__((ext_vector_type(8)))  unsigned short u16x8;

__device__ __forceinline__ unsigned short f2bf(float f) {
    return __builtin_bit_cast(unsigned short, static_cast<__bf16>(f));
}

// swizzled LDS element index for (row r, k in 0..31), 16B-unit XOR swizzle
// verified conflict-free (rounds 1-3: SQ_LDS_BANK_CONFLICT == 0)
__device__ __forceinline__ int swzidx(int r, int k) {
    return r * 32 + ((((k >> 3) ^ ((r >> 1) & 3)) << 3) | (k & 7));
}

struct Stage {          // one prefetch set: 24 VGPRs
    f32x4 av[4];
    float bv[8];
};

// (512,2): cap 256 VGPR/wave — room for acc(64)+2 stage sets(48)+addressing,
// NO forced spill (round-3 lesson: (512,6) spilled acc -> 9.2 GB scratch traffic)
__global__ void __launch_bounds__(512, 2)
dense_local(const float* __restrict__ X, const float* __restrict__ Kn,
            float* __restrict__ Out)
{
    __shared__ __align__(16) unsigned short lA[2][256 * 32];  // 32 KB
    __shared__ __align__(16) unsigned short lB[2][128 * 32];  // 16 KB

    // XCD swizzle: 2048 wgs, 256/XCD, k-major inside an XCD chunk (bijective)
    const int bid  = blockIdx.x;
    const int wg   = (bid & 7) * 256 + (bid >> 3);
    const int kidx = wg >> 4;          // 0..127
    const int tile = wg & 15;
    const int mt   = tile >> 3;        // 0..1  (M tiles of 256 over 512)
    const int nt   = tile & 7;         // 0..7  (N tiles of 128 over 1024)

    const int t   = threadIdx.x;
    const int l   = t & 63;
    const int w   = t >> 6;            // 0..7
    const int wm  = w >> 1;            // wave m-quadrant (64 rows)
    const int wn  = w & 1;             // wave n-half (64 cols)
    const int l15 = l & 15, g = l >> 4;

    const size_t MROW = (size_t)NKER * INDIM; // 131072

    const float* Abase = X   + (size_t)mt * 256 * MROW + (size_t)kidx * INDIM;
    const float* Bbase = Kn  + (size_t)kidx * INDIM * UNITS + nt * 128;
    float*       Cbase = Out + (size_t)mt * 256 * MROW + (size_t)kidx * UNITS + nt * 128;

    // staging maps (verified)
    const int ar0 = t >> 3;            // A rows 0..63 (+p*64)
    const int ak4 = (t & 7) << 2;      // A k-quad
    const int bn  = t & 127;           // B column (lane-consecutive)
    const int bkh = t >> 7;            // B k-octet 0..3

    // per-thread, per-set running pointers (strength-reduced addressing)
    const float* aTh = Abase + (size_t)ar0 * MROW + ak4;
    const float* bTh = Bbase + (size_t)bkh * 8 * UNITS + bn;
    const float* aP0 = aTh;                const float* bP0 = bTh;
    const float* aP1 = aTh + 32;           const float* bP1 = bTh + (size_t)32 * UNITS;

    f32x4 acc[4][4];
#pragma unroll
    for (int mi = 0; mi < 4; ++mi)
#pragma unroll
        for (int ni = 0; ni < 4; ++ni)
            acc[mi][ni] = f32x4{0.f, 0.f, 0.f, 0.f};

    Stage S0, S1;

    auto loadg = [&](Stage& S, const float*& aP, const float*& bP) {
#pragma unroll
        for (int p = 0; p < 4; ++p)
            S.av[p] = *(const f32x4*)(aP + (size_t)p * 64 * MROW);
#pragma unroll
        for (int j = 0; j < 8; ++j)
            S.bv[j] = bP[(size_t)j * UNITS];   // 64 consecutive lanes = 256B
        aP += 64;                               // advance one same-set K-step (2*32)
        bP += (size_t)64 * UNITS;
    };

    auto writes = [&](const Stage& S, int bb) {
#pragma unroll
        for (int p = 0; p < 4; ++p) {
            u16x4 h;
#pragma unroll
            for (int c = 0; c < 4; ++c) h[c] = f2bf(S.av[p][c]);
            *(u16x4*)&lA[bb][swzidx(ar0 + p * 64, ak4)] = h;
        }
        u16x8 h0;
#pragma unroll
        for (int j = 0; j < 8; ++j) h0[j] = f2bf(S.bv[j]);
        *(u16x8*)&lB[bb][swzidx(bn, bkh * 8)] = h0;  // transpose: row=n, k-contig
    };

    auto compute = [&](int bb) {
        bf16x8 af[4], bfr[4];
#pragma unroll
        for (int mi = 0; mi < 4; ++mi)
            af[mi] = *(const bf16x8*)&lA[bb][swzidx(wm * 64 + mi * 16 + l15, g * 8)];
#pragma unroll
        for (int ni = 0; ni < 4; ++ni)
            bfr[ni] = *(const bf16x8*)&lB[bb][swzidx(wn * 64 + ni * 16 + l15, g * 8)];
#pragma unroll
        for (int mi = 0; mi < 4; ++mi)
#pragma unroll
            for (int ni = 0; ni < 4; ++ni)
                acc[mi][ni] = __builtin_amdgcn_mfma_f32_16x16x32_bf16(
                    af[mi], bfr[ni], acc[mi][ni], 0, 0, 0);
    };

    // --- depth-2 pipelined prologue ---
    loadg(S0, aP0, bP0);     // K-step 0
    loadg(S1, aP1, bP1);     // K-step 1 (stays in flight across the S0 wait)
    writes(S0, 0);           // counted vmcnt: waits S0, leaves S1 flying
    __syncthreads();

    // --- main loop: 32 K-steps, unrolled x2, static reg sets (rule #20) ---
#pragma unroll 1
    for (int it = 0; it < 16; ++it) {
        // even step 2it: compute buf0
        if (it < 15) loadg(S0, aP0, bP0);   // data for step 2it+2
        compute(0);
        __syncthreads();
        writes(S1, 1);                       // waits S1 (issued a full step ago)
        __syncthreads();
        // odd step 2it+1: compute buf1
        if (it < 15) loadg(S1, aP1, bP1);   // data for step 2it+3
        compute(1);
        __syncthreads();
        if (it < 15) writes(S0, 0);          // data for step 2it+2
        __syncthreads();
    }

    // epilogue: softplus + store (C/D: col=lane&15, row=(lane>>4)*4+reg)
#pragma unroll
    for (int mi = 0; mi < 4; ++mi) {
#pragma unroll
        for (int ni = 0; ni < 4; ++ni) {
            const int n = wn * 64 + ni * 16 + l15;
#pragma unroll
            for (int r = 0; r < 4; ++r) {
                const int m = wm * 64 + mi * 16 + g * 4 + r;
                const float v  = acc[mi][ni][r];
                const float sp = fmaxf(v, 0.0f) + log1pf(__expf(-fabsf(v)));
                Cbase[(size_t)m * MROW + n] = sp;
            }
        }
    }
}

extern "C" void kernel_launch(void* const* d_in, const int* in_sizes, int n_in,
                              void* d_out, int out_size, void* d_ws, size_t ws_size,
                              hipStream_t stream) {
    const float* X  = (const float*)d_in[0];
    const float* Kn = (const float*)d_in[1];
    float* O = (float*)d_out;
    dense_local<<<2048, 512, 0, stream>>>(X, Kn, O);
}

// Round 5
// 453.073 us; speedup vs baseline: 4.8113x; 1.0704x over previous
//
#include <hip/hip_runtime.h>

#define NKER  128
#define INDIM 1024
#define UNITS 1024

typedef __attribute__((ext_vector_type(8)))  short          bf16x8;
typedef __attribute__((ext_vector_type(4)))  float          f32x4;
typedef __attribute__((ext_vector_type(4)))  unsigned short u16x4;
typedef __attribute__((ext_vector_type(8)))  unsigned short u16x8;

// raw barrier discipline (T3/T4): s_barrier does NOT drain vmcnt, unlike
// __syncthreads(). We drain lgkm (LDS) explicitly where cross-wave LDS
// dependencies require it; global loads stay in flight across barriers and
// get compiler-inserted COUNTED vmcnt waits at their register uses.
#define LGKM0   asm volatile("s_waitcnt lgkmcnt(0)" ::: "memory")
#define BAR()   __builtin_amdgcn_s_barrier()
#define SCHED0  __builtin_amdgcn_sched_barrier(0)

__device__ __forceinline__ unsigned short f2bf(float f) {
    return __builtin_bit_cast(unsigned short, static_cast<__bf16>(f));
}

// swizzled LDS element index for (row r, k in 0..31), 16B-unit XOR swizzle
// verified conflict-free (rounds 1-4: SQ_LDS_BANK_CONFLICT == 0)
__device__ __forceinline__ int swzidx(int r, int k) {
    return r * 32 + ((((k >> 3) ^ ((r >> 1) & 3)) << 3) | (k & 7));
}

struct Stage {          // one prefetch set: 24 VGPRs
    f32x4 av[4];
    float bv[8];
};

__global__ void __launch_bounds__(512, 2)
dense_local(const float* __restrict__ X, const float* __restrict__ Kn,
            float* __restrict__ Out)
{
    __shared__ __align__(16) unsigned short lA[2][256 * 32];  // 32 KB
    __shared__ __align__(16) unsigned short lB[2][128 * 32];  // 16 KB

    // XCD swizzle: 2048 wgs, 256/XCD, k-major inside an XCD chunk (bijective)
    const int bid  = blockIdx.x;
    const int wg   = (bid & 7) * 256 + (bid >> 3);
    const int kidx = wg >> 4;          // 0..127
    const int tile = wg & 15;
    const int mt   = tile >> 3;        // 0..1  (M tiles of 256 over 512)
    const int nt   = tile & 7;         // 0..7  (N tiles of 128 over 1024)

    const int t   = threadIdx.x;
    const int l   = t & 63;
    const int w   = t >> 6;            // 0..7
    const int wm  = w >> 1;            // wave m-quadrant (64 rows)
    const int wn  = w & 1;             // wave n-half (64 cols)
    const int l15 = l & 15, g = l >> 4;

    const size_t MROW = (size_t)NKER * INDIM; // 131072

    const float* Abase = X   + (size_t)mt * 256 * MROW + (size_t)kidx * INDIM;
    const float* Bbase = Kn  + (size_t)kidx * INDIM * UNITS + nt * 128;
    float*       Cbase = Out + (size_t)mt * 256 * MROW + (size_t)kidx * UNITS + nt * 128;

    // staging maps (verified)
    const int ar0 = t >> 3;            // A rows 0..63 (+p*64)
    const int ak4 = (t & 7) << 2;      // A k-quad
    const int bn  = t & 127;           // B column (lane-consecutive)
    const int bkh = t >> 7;            // B k-octet 0..3

    // per-thread, per-set running pointers
    const float* aTh = Abase + (size_t)ar0 * MROW + ak4;
    const float* bTh = Bbase + (size_t)bkh * 8 * UNITS + bn;
    const float* aP0 = aTh;                const float* bP0 = bTh;
    const float* aP1 = aTh + 32;           const float* bP1 = bTh + (size_t)32 * UNITS;

    f32x4 acc[4][4];
#pragma unroll
    for (int mi = 0; mi < 4; ++mi)
#pragma unroll
        for (int ni = 0; ni < 4; ++ni)
            acc[mi][ni] = f32x4{0.f, 0.f, 0.f, 0.f};

    Stage S0, S1;

    auto loadg = [&](Stage& S, const float*& aP, const float*& bP) {
#pragma unroll
        for (int p = 0; p < 4; ++p)
            S.av[p] = *(const f32x4*)(aP + (size_t)p * 64 * MROW);
#pragma unroll
        for (int j = 0; j < 8; ++j)
            S.bv[j] = bP[(size_t)j * UNITS];   // 64 consecutive lanes = 256B
        aP += 64;                               // next same-set K-step (2*32)
        bP += (size_t)64 * UNITS;
    };

    auto writes = [&](const Stage& S, int bb) {
        // compiler inserts a COUNTED vmcnt here (12 newer loads in flight)
#pragma unroll
        for (int p = 0; p < 4; ++p) {
            u16x4 h;
#pragma unroll
            for (int c = 0; c < 4; ++c) h[c] = f2bf(S.av[p][c]);
            *(u16x4*)&lA[bb][swzidx(ar0 + p * 64, ak4)] = h;
        }
        u16x8 h0;
#pragma unroll
        for (int j = 0; j < 8; ++j) h0[j] = f2bf(S.bv[j]);
        *(u16x8*)&lB[bb][swzidx(bn, bkh * 8)] = h0;  // transpose: row=n, k-contig
    };

    auto compute = [&](int bb) {
        bf16x8 af[4], bfr[4];
#pragma unroll
        for (int mi = 0; mi < 4; ++mi)
            af[mi] = *(const bf16x8*)&lA[bb][swzidx(wm * 64 + mi * 16 + l15, g * 8)];
#pragma unroll
        for (int ni = 0; ni < 4; ++ni)
            bfr[ni] = *(const bf16x8*)&lB[bb][swzidx(wn * 64 + ni * 16 + l15, g * 8)];
        LGKM0;          // fragment ds_reads complete BEFORE the next barrier
        SCHED0;         // rule #18: keep MFMA below the wait
        __builtin_amdgcn_s_setprio(1);
#pragma unroll
        for (int mi = 0; mi < 4; ++mi)
#pragma unroll
            for (int ni = 0; ni < 4; ++ni)
                acc[mi][ni] = __builtin_amdgcn_mfma_f32_16x16x32_bf16(
                    af[mi], bfr[ni], acc[mi][ni], 0, 0, 0);
        __builtin_amdgcn_s_setprio(0);
    };

    // --- depth-2 pipelined prologue ---
    loadg(S0, aP0, bP0);     // K-step 0 (12 vmem)
    loadg(S1, aP1, bP1);     // K-step 1 (12 vmem, stays in flight)
    writes(S0, 0);           // compiler vmcnt(12): waits step-0, leaves step-1 flying
    LGKM0;                   // own ds_writes committed
    BAR();

    // --- main loop: steps 0..29 as 15 pairs, static reg sets (rule #20) ---
#pragma unroll 1
    for (int it = 0; it < 15; ++it) {
        // even step t=2it: compute buf0
        loadg(S0, aP0, bP0);             // loads for step 2it+2
        compute(0);                       // reads buf0 (incl. LGKM0 drain)
        BAR();                            // all waves done reading buf0/writing buf1 deps
        writes(S1, 1);                    // step 2it+1 data; counted vmcnt(12)
        LGKM0;
        BAR();
        // odd step t=2it+1: compute buf1
        loadg(S1, aP1, bP1);             // loads for step 2it+3
        compute(1);
        BAR();
        writes(S0, 0);                    // step 2it+2 data; counted vmcnt(12)
        LGKM0;
        BAR();
    }

    // --- peeled tail: steps 30, 31 (no further loads; natural vmcnt(0)) ---
    compute(0);              // step 30
    BAR();
    writes(S1, 1);           // step 31 data (no newer loads -> vmcnt(0))
    LGKM0;
    BAR();
    compute(1);              // step 31

    // epilogue: softplus + store (C/D: col=lane&15, row=(lane>>4)*4+reg)
#pragma unroll
    for (int mi = 0; mi < 4; ++mi) {
#pragma unroll
        for (int ni = 0; ni < 4; ++ni) {
            const int n = wn * 64 + ni * 16 + l15;
#pragma unroll
            for (int r = 0; r < 4; ++r) {
                const int m = wm * 64 + mi * 16 + g * 4 + r;
                const float v  = acc[mi][ni][r];
                const float sp = fmaxf(v, 0.0f) + log1pf(__expf(-fabsf(v)));
                Cbase[(size_t)m * MROW + n] = sp;
            }
        }
    }
}

extern "C" void kernel_launch(void* const* d_in, const int* in_sizes, int n_in,
                              void* d_out, int out_size, void* d_ws, size_t ws_size,
                              hipStream_t stream) {
    const float* X  = (const float*)d_in[0];
    const float* Kn = (const float*)d_in[1];
    float* O = (float*)d_out;
    dense_local<<<2048, 512, 0, stream>>>(X, Kn, O);
}